// Round 8
// baseline (29.873 us; speedup 1.0000x reference)
//
#include <hip/hip_runtime.h>

#define NQ 11

// Two samples per wave (A and B), each a 2048-amplitude real statevector in
// 16 float2 VGPRs.  Amplitude index i (wire w <-> bit (10-w) of i):
//   i = (k<<7) | (comp<<6) | lane
//   wires 0..3  -> k bits 3..0    (packed float2 register butterflies)
//   wire  4     -> comp           (within-float2 butterfly)
//   wires 5..10 -> lane bits 5..0 (cross-lane butterflies)
// CZ gates folded into the NEXT RY's coefficients (verified r3/r5/r6).
// Cross-lane: mask 32/16 -> __shfl_xor with BATCHED fetches (one waitcnt
// drain per gate); masks 8,4,2,1 -> DPP (verified r5/r6).
// Two independent per-sample dataflow chains interleaved at the k-loop level
// give ILP=2 to hide DS/DPP latency at 1 wave/SIMD (1024 waves total).

typedef float f32x2 __attribute__((ext_vector_type(2)));

__device__ __forceinline__ f32x2 b2(float s) { f32x2 r; r.x = s; r.y = s; return r; }
__device__ __forceinline__ f32x2 fma2(f32x2 a, f32x2 b, f32x2 c) {
    return __builtin_elementwise_fma(a, b, c);
}

template <int CTRL>
__device__ __forceinline__ float dpp_mov(float x) {
    const int xi = __builtin_bit_cast(int, x);
    return __builtin_bit_cast(float,
        __builtin_amdgcn_update_dpp(xi, xi, CTRL, 0xf, 0xf, false));
}
#define DPP_XOR1 0xB1   // quad_perm [1,0,3,2]
#define DPP_XOR2 0x4E   // quad_perm [2,3,0,1]
#define DPP_XOR3 0x1B   // quad_perm [3,2,1,0]
#define DPP_XOR7 0x141  // row_half_mirror
#define DPP_XOR8 0x128  // row_ror:8 (xor-8 within 16-lane row)

// Packed register butterfly on k-bit KB for BOTH states; preceding CZ sign:
// -1 iff (k0 & KSB).
#define RY_K_F2(KB, KSB, C, S)                                               \
    {                                                                        \
        const f32x2 Cv = b2(C), Sv = b2(S);                                  \
        _Pragma("unroll")                                                    \
        for (int g = 0; g < 8; ++g) {                                        \
            const int k0 = ((g >> (KB)) << ((KB) + 1)) | (g & ((1 << (KB)) - 1)); \
            const int k1 = k0 | (1 << (KB));                                 \
            const f32x2 aA = vA[k0], bA = vA[k1];                            \
            const f32x2 aB = vB[k0], bB = vB[k1];                            \
            if (k0 & (KSB)) {                                                \
                vA[k0] = fma2(Cv, aA, Sv * bA);                              \
                vA[k1] = fma2(Sv, aA, -(Cv * bA));                           \
                vB[k0] = fma2(Cv, aB, Sv * bB);                              \
                vB[k1] = fma2(Sv, aB, -(Cv * bB));                           \
            } else {                                                         \
                vA[k0] = fma2(Cv, aA, -(Sv * bA));                           \
                vA[k1] = fma2(Sv, aA, Cv * bA);                              \
                vB[k0] = fma2(Cv, aB, -(Sv * bB));                           \
                vB[k1] = fma2(Sv, aB, Cv * bB);                              \
            }                                                                \
        }                                                                    \
    }

// DS shuffle gate, BATCHED: all 64 partner fetches (2 samples x 32 words)
// issued before any use -> single waitcnt drain, latency amortized.
#define RY_DS2(SHFL, CV, SV)                                                 \
    {                                                                        \
        f32x2 pA[16], pB[16];                                                \
        _Pragma("unroll")                                                    \
        for (int k = 0; k < 16; ++k) {                                       \
            pA[k].x = SHFL(vA[k].x); pA[k].y = SHFL(vA[k].y);                \
            pB[k].x = SHFL(vB[k].x); pB[k].y = SHFL(vB[k].y);                \
        }                                                                    \
        _Pragma("unroll")                                                    \
        for (int k = 0; k < 16; ++k) {                                       \
            vA[k] = fma2(CV, vA[k], (SV) * pA[k]);                           \
            vB[k] = fma2(CV, vB[k], (SV) * pB[k]);                           \
        }                                                                    \
    }

// DPP lane gate for both states (VALU pipe, short latency).
#define RY_DPP2(PGETX, CV, SV)                                               \
    _Pragma("unroll")                                                        \
    for (int k = 0; k < 16; ++k) {                                           \
        f32x2 pa, pb;                                                        \
        pa.x = PGETX(vA[k].x); pa.y = PGETX(vA[k].y);                        \
        pb.x = PGETX(vB[k].x); pb.y = PGETX(vB[k].y);                        \
        vA[k] = fma2(CV, vA[k], (SV) * pa);                                  \
        vB[k] = fma2(CV, vB[k], (SV) * pb);                                  \
    }

__global__ __launch_bounds__(256, 1) void qru_kernel(
    const float* __restrict__ x,   // [2048, 16]
    const float* __restrict__ w,   // [11]
    float* __restrict__ out)       // [2048, 11]
{
    const int lane = threadIdx.x & 63;
    const int g    = blockIdx.x * 4 + (threadIdx.x >> 6);  // wave id 0..1023
    const int nA   = 2 * g, nB = 2 * g + 1;

    // ---- input angles (vectorized) + half-angle sin/cos, both samples ----
    const float4 a0 = *(const float4*)(x + nA * 16);
    const float4 a1 = *(const float4*)(x + nA * 16 + 4);
    const float4 a2 = *(const float4*)(x + nA * 16 + 8);
    const float4 b0 = *(const float4*)(x + nB * 16);
    const float4 b1 = *(const float4*)(x + nB * 16 + 4);
    const float4 b2_ = *(const float4*)(x + nB * 16 + 8);
    const float xvA[NQ] = {a0.x, a0.y, a0.z, a0.w, a1.x, a1.y, a1.z, a1.w,
                           a2.x, a2.y, a2.z};
    const float xvB[NQ] = {b0.x, b0.y, b0.z, b0.w, b1.x, b1.y, b1.z, b1.w,
                           b2_.x, b2_.y, b2_.z};
    float ciA[NQ], siA[NQ], ciB[NQ], siB[NQ];
#pragma unroll
    for (int q = 0; q < NQ; ++q) {
        const float hA = xvA[q] * 0.5f, hB = xvB[q] * 0.5f;
        siA[q] = __sinf(hA); ciA[q] = __cosf(hA);
        siB[q] = __sinf(hB); ciB[q] = __cosf(hB);
    }
    float cw[NQ], sw[NQ];
#pragma unroll
    for (int q = 0; q < NQ; ++q) {
        const float h = w[q] * 0.5f;
        sw[q] = __sinf(h); cw[q] = __cosf(h);
    }

    // ---- initial product states ----
    const float laneFA =
        ((lane & 32) ? siA[5]  : ciA[5])  *
        ((lane & 16) ? siA[6]  : ciA[6])  *
        ((lane & 8)  ? siA[7]  : ciA[7])  *
        ((lane & 4)  ? siA[8]  : ciA[8])  *
        ((lane & 2)  ? siA[9]  : ciA[9])  *
        ((lane & 1)  ? siA[10] : ciA[10]);
    const float laneFB =
        ((lane & 32) ? siB[5]  : ciB[5])  *
        ((lane & 16) ? siB[6]  : ciB[6])  *
        ((lane & 8)  ? siB[7]  : ciB[7])  *
        ((lane & 4)  ? siB[8]  : ciB[8])  *
        ((lane & 2)  ? siB[9]  : ciB[9])  *
        ((lane & 1)  ? siB[10] : ciB[10]);

    f32x2 vA[16], vB[16];
#pragma unroll
    for (int k = 0; k < 16; ++k) {
        const float bA = laneFA * ((k & 8) ? siA[0] : ciA[0])
                                * ((k & 4) ? siA[1] : ciA[1])
                                * ((k & 2) ? siA[2] : ciA[2])
                                * ((k & 1) ? siA[3] : ciA[3]);
        vA[k].x = bA * ciA[4];
        vA[k].y = bA * siA[4];
        const float bB = laneFB * ((k & 8) ? siB[0] : ciB[0])
                                * ((k & 4) ? siB[1] : ciB[1])
                                * ((k & 2) ? siB[2] : ciB[2])
                                * ((k & 1) ? siB[3] : ciB[3]);
        vB[k].x = bB * ciB[4];
        vB[k].y = bB * siB[4];
    }

    // ---- folded per-lane coefficient constants (verified r3/r5/r6),
    //      all sample-independent (lane + weights only) ----
    const float X0m = (lane & 1) ?  sw[0] : -sw[0];
    const float Y0m = (lane & 1) ? -cw[0] :  cw[0];
    const float SS5 = (lane & 32) ?  sw[5] : -sw[5];
    const float C5m = (lane & 32) ? -cw[5] :  cw[5];
    f32x2 Cv5; Cv5.x = cw[5]; Cv5.y = C5m;
    f32x2 Sv5; Sv5.x = SS5;   Sv5.y = sw[5];
    const f32x2 C6v  = b2(((lane & 48) == 48) ? -cw[6]  : cw[6]);
    const f32x2 S6v  = b2((lane & 48) ? sw[6]  : -sw[6]);
    const f32x2 C7v  = b2(((lane & 24) == 24) ? -cw[7]  : cw[7]);
    const f32x2 S7v  = b2((lane & 24) ? sw[7]  : -sw[7]);
    const f32x2 C8v  = b2(((lane & 12) == 12) ? -cw[8]  : cw[8]);
    const f32x2 S8v  = b2((lane & 12) ? sw[8]  : -sw[8]);
    const f32x2 C9v  = b2(((lane & 6)  == 6)  ? -cw[9]  : cw[9]);
    const f32x2 S9v  = b2((lane & 6)  ? sw[9]  : -sw[9]);
    const f32x2 C10v = b2(((lane & 3)  == 3)  ? -cw[10] : cw[10]);
    const f32x2 S10v = b2((lane & 3)  ? sw[10] : -sw[10]);

    // RY4 (comp butterfly), incoming CZ(3,4): sigma1 = -1 iff k odd.
    f32x2 C4p; C4p.x = cw[4];  C4p.y =  cw[4];
    f32x2 S4p; S4p.x = -sw[4]; S4p.y =  sw[4];
    f32x2 C4m; C4m.x = cw[4];  C4m.y = -cw[4];
    f32x2 S4m; S4m.x = sw[4];  S4m.y =  sw[4];

    auto shfl32 = [](float t) { return __shfl_xor(t, 32); };
    auto shfl16 = [](float t) { return __shfl_xor(t, 16); };
    auto dppx8  = [](float t) { return dpp_mov<DPP_XOR8>(t); };
    auto dppx4  = [](float t) { return dpp_mov<DPP_XOR3>(dpp_mov<DPP_XOR7>(t)); };
    auto dppx2  = [](float t) { return dpp_mov<DPP_XOR2>(t); };
    auto dppx1  = [](float t) { return dpp_mov<DPP_XOR1>(t); };

    auto layer = [&](float X0, float Y0) {
        // RY0 on k bit 3 (incoming CZ folded into X0/Y0), both samples
        {
            const f32x2 c0 = b2(cw[0]), s0 = b2(sw[0]);
            const f32x2 x0 = b2(X0),    y0 = b2(Y0);
#pragma unroll
            for (int k = 0; k < 8; ++k) {
                const f32x2 aA = vA[k], bA = vA[k | 8];
                vA[k]     = fma2(c0, aA, x0 * bA);
                vA[k | 8] = fma2(s0, aA, y0 * bA);
                const f32x2 aB = vB[k], bB = vB[k | 8];
                vB[k]     = fma2(c0, aB, x0 * bB);
                vB[k | 8] = fma2(s0, aB, y0 * bB);
            }
        }
        RY_K_F2(2, 8, cw[1], sw[1])     // RY1, fold CZ(0,1)
        RY_K_F2(1, 4, cw[2], sw[2])     // RY2, fold CZ(1,2)
        RY_K_F2(0, 2, cw[3], sw[3])     // RY3, fold CZ(2,3)

        // RY4 (component), fold CZ(3,4) (k bit0), both samples
#pragma unroll
        for (int k = 0; k < 16; ++k) {
            const f32x2 sA = __builtin_shufflevector(vA[k], vA[k], 1, 0);
            const f32x2 sB = __builtin_shufflevector(vB[k], vB[k], 1, 0);
            vA[k] = (k & 1) ? fma2(C4m, vA[k], S4m * sA)
                            : fma2(C4p, vA[k], S4p * sA);
            vB[k] = (k & 1) ? fma2(C4m, vB[k], S4m * sB)
                            : fma2(C4p, vB[k], S4p * sB);
        }

        RY_DS2(shfl32, Cv5, Sv5)        // RY5,  fold CZ(4,5)  — DS batched
        RY_DS2(shfl16, C6v, S6v)        // RY6,  fold CZ(5,6)  — DS batched
        RY_DPP2(dppx8, C7v,  S7v)       // RY7,  fold CZ(6,7)  — DPP
        RY_DPP2(dppx4, C8v,  S8v)       // RY8,  fold CZ(7,8)  — DPP x2
        RY_DPP2(dppx2, C9v,  S9v)       // RY9,  fold CZ(8,9)  — DPP
        RY_DPP2(dppx1, C10v, S10v)      // RY10, fold CZ(9,10) — DPP
        // CZ(10,0) -> folded into next layer's RY0; pure sign after last.
    };

    layer(-sw[0], cw[0]);               // layer 0: RY0 has no incoming CZ
#pragma unroll 1
    for (int l = 1; l < 6; ++l) layer(X0m, Y0m);

    // ---- measurement: out[w] = sum_i amp_i^2 * (1 - 2*bit_w(i)) ----
    f32x2 TA = b2(0.f), A3 = b2(0.f), A2 = b2(0.f), A1 = b2(0.f), A0 = b2(0.f);
    f32x2 TB = b2(0.f), B3 = b2(0.f), B2 = b2(0.f), B1 = b2(0.f), B0 = b2(0.f);
#pragma unroll
    for (int k = 0; k < 16; ++k) {
        const f32x2 pA = vA[k] * vA[k];
        const f32x2 pB = vB[k] * vB[k];
        TA = TA + pA;  TB = TB + pB;
        if (k & 8) { A3 = A3 + pA; B3 = B3 + pB; }
        if (k & 4) { A2 = A2 + pA; B2 = B2 + pB; }
        if (k & 2) { A1 = A1 + pA; B1 = B1 + pB; }
        if (k & 1) { A0 = A0 + pA; B0 = B0 + pB; }
    }
    const float totA = TA.x + TA.y, totB = TB.x + TB.y;

    float qA[NQ], qB[NQ];
    qA[0] = totA - 2.f * (A3.x + A3.y);  qB[0] = totB - 2.f * (B3.x + B3.y);
    qA[1] = totA - 2.f * (A2.x + A2.y);  qB[1] = totB - 2.f * (B2.x + B2.y);
    qA[2] = totA - 2.f * (A1.x + A1.y);  qB[2] = totB - 2.f * (B1.x + B1.y);
    qA[3] = totA - 2.f * (A0.x + A0.y);  qB[3] = totB - 2.f * (B0.x + B0.y);
    qA[4] = totA - 2.f * TA.y;           qB[4] = totB - 2.f * TB.y;
    qA[5]  = (lane & 32) ? -totA : totA; qB[5]  = (lane & 32) ? -totB : totB;
    qA[6]  = (lane & 16) ? -totA : totA; qB[6]  = (lane & 16) ? -totB : totB;
    qA[7]  = (lane & 8)  ? -totA : totA; qB[7]  = (lane & 8)  ? -totB : totB;
    qA[8]  = (lane & 4)  ? -totA : totA; qB[8]  = (lane & 4)  ? -totB : totB;
    qA[9]  = (lane & 2)  ? -totA : totA; qB[9]  = (lane & 2)  ? -totB : totB;
    qA[10] = (lane & 1)  ? -totA : totA; qB[10] = (lane & 1)  ? -totB : totB;

    // stage-major wave reduction: 22 independent DS ops per DS stage
#pragma unroll
    for (int wq = 0; wq < NQ; ++wq) { qA[wq] += __shfl_xor(qA[wq], 32);
                                      qB[wq] += __shfl_xor(qB[wq], 32); }
#pragma unroll
    for (int wq = 0; wq < NQ; ++wq) { qA[wq] += __shfl_xor(qA[wq], 16);
                                      qB[wq] += __shfl_xor(qB[wq], 16); }
#pragma unroll
    for (int wq = 0; wq < NQ; ++wq) { qA[wq] += dpp_mov<DPP_XOR8>(qA[wq]);
                                      qB[wq] += dpp_mov<DPP_XOR8>(qB[wq]); }
#pragma unroll
    for (int wq = 0; wq < NQ; ++wq) {
        qA[wq] += dpp_mov<DPP_XOR3>(dpp_mov<DPP_XOR7>(qA[wq]));
        qB[wq] += dpp_mov<DPP_XOR3>(dpp_mov<DPP_XOR7>(qB[wq]));
    }
#pragma unroll
    for (int wq = 0; wq < NQ; ++wq) { qA[wq] += dpp_mov<DPP_XOR2>(qA[wq]);
                                      qB[wq] += dpp_mov<DPP_XOR2>(qB[wq]); }
#pragma unroll
    for (int wq = 0; wq < NQ; ++wq) { qA[wq] += dpp_mov<DPP_XOR1>(qA[wq]);
                                      qB[wq] += dpp_mov<DPP_XOR1>(qB[wq]); }

    if (lane == 0) {
#pragma unroll
        for (int wq = 0; wq < NQ; ++wq) {
            out[nA * NQ + wq] = qA[wq];
            out[nB * NQ + wq] = qB[wq];
        }
    }
}

extern "C" void kernel_launch(void* const* d_in, const int* in_sizes, int n_in,
                              void* d_out, int out_size, void* d_ws, size_t ws_size,
                              hipStream_t stream) {
    const float* x = (const float*)d_in[0];   // [8,256,16] f32
    const float* w = (const float*)d_in[1];   // [11] f32
    float* out = (float*)d_out;               // [8,256,11] f32

    // 2048 samples, 2 per wave, 4 waves per block -> 256 blocks
    qru_kernel<<<256, 256, 0, stream>>>(x, w, out);
}

// Round 9
// 24.850 us; speedup vs baseline: 1.2021x; 1.2021x over previous
//
#include <hip/hip_runtime.h>

#define NQ 11

// One wave per sample; 2048-amplitude real statevector in 16 float2 VGPR
// pairs per lane.  Amplitude index i (wire w <-> bit (10-w) of i):
//   i = (k<<7) | (comp<<6) | lane
//   wires 0..3  -> k bits 3..0    (packed float2 register butterflies)
//   wire  4     -> comp           (within-float2 butterfly)
//   wires 5..10 -> lane bits 5..0 (cross-lane butterflies)
// CZ gates folded into the NEXT RY's coefficients (verified r3/r5/r6).
// Cross-lane: mask 32/16 -> __shfl_xor with BATCHED partner fetches (all 32
// bpermutes issued before any use -> one lgkmcnt drain per gate instead of
// ~32 serialized round-trips); masks 8,4,2,1 -> DPP (verified r5/r6).
// permlane{32,16}_swap abandoned: algebra + probe verified, dense-loop use
// still corrupts (suspected codegen issue with the two-result intrinsic).

typedef float f32x2 __attribute__((ext_vector_type(2)));

__device__ __forceinline__ f32x2 b2(float s) { f32x2 r; r.x = s; r.y = s; return r; }
__device__ __forceinline__ f32x2 fma2(f32x2 a, f32x2 b, f32x2 c) {
    return __builtin_elementwise_fma(a, b, c);
}

template <int CTRL>
__device__ __forceinline__ float dpp_mov(float x) {
    const int xi = __builtin_bit_cast(int, x);
    return __builtin_bit_cast(float,
        __builtin_amdgcn_update_dpp(xi, xi, CTRL, 0xf, 0xf, false));
}
#define DPP_XOR1 0xB1   // quad_perm [1,0,3,2]
#define DPP_XOR2 0x4E   // quad_perm [2,3,0,1]
#define DPP_XOR3 0x1B   // quad_perm [3,2,1,0]
#define DPP_XOR7 0x141  // row_half_mirror
#define DPP_XOR8 0x128  // row_ror:8 (xor-8 within 16-lane row)

// Packed butterfly on k-bit KB; preceding CZ sign: -1 iff (k0 & KSB).
#define RY_K_F(KB, KSB, C, S)                                                \
    _Pragma("unroll")                                                        \
    for (int g = 0; g < 8; ++g) {                                            \
        const int k0 = ((g >> (KB)) << ((KB) + 1)) | (g & ((1 << (KB)) - 1));\
        const int k1 = k0 | (1 << (KB));                                     \
        const f32x2 a_ = v2[k0], b_ = v2[k1];                                \
        const f32x2 Cv = b2(C), Sv = b2(S);                                  \
        if (k0 & (KSB)) {                                                    \
            v2[k0] = fma2(Cv, a_, Sv * b_);                                  \
            v2[k1] = fma2(Sv, a_, -(Cv * b_));                               \
        } else {                                                             \
            v2[k0] = fma2(Cv, a_, -(Sv * b_));                               \
            v2[k1] = fma2(Sv, a_, Cv * b_);                                  \
        }                                                                    \
    }

// DS shuffle gate, BATCHED: all 32 partner fetches issued before any use ->
// single waitcnt drain, DS latency amortized across the batch.
#define RY_DS_B(SHFL, CV, SV)                                                \
    {                                                                        \
        f32x2 pa_[16];                                                       \
        _Pragma("unroll")                                                    \
        for (int k = 0; k < 16; ++k) {                                       \
            pa_[k].x = SHFL(v2[k].x);                                        \
            pa_[k].y = SHFL(v2[k].y);                                        \
        }                                                                    \
        _Pragma("unroll")                                                    \
        for (int k = 0; k < 16; ++k)                                         \
            v2[k] = fma2(CV, v2[k], (SV) * pa_[k]);                          \
    }

// DPP lane gate (VALU pipe, short latency) — no batching needed.
#define RY_DPP(PGETX, CV, SV)                                                \
    _Pragma("unroll")                                                        \
    for (int k = 0; k < 16; ++k) {                                           \
        f32x2 pa_;                                                           \
        pa_.x = PGETX(v2[k].x);                                              \
        pa_.y = PGETX(v2[k].y);                                              \
        v2[k] = fma2(CV, v2[k], (SV) * pa_);                                 \
    }

__global__ __launch_bounds__(256, 2) void qru_kernel(
    const float* __restrict__ x,   // [2048, 16]
    const float* __restrict__ w,   // [11]
    float* __restrict__ out)       // [2048, 11]
{
    const int lane = threadIdx.x & 63;
    const int n    = blockIdx.x * 4 + (threadIdx.x >> 6);

    // ---- input angles (vectorized) + half-angle sin/cos ----
    const float4 xa = *(const float4*)(x + n * 16);
    const float4 xb = *(const float4*)(x + n * 16 + 4);
    const float4 xc = *(const float4*)(x + n * 16 + 8);
    const float xv[NQ] = {xa.x, xa.y, xa.z, xa.w, xb.x, xb.y, xb.z, xb.w,
                          xc.x, xc.y, xc.z};
    float ci[NQ], si[NQ];
#pragma unroll
    for (int q = 0; q < NQ; ++q) {
        const float h = xv[q] * 0.5f;
        si[q] = __sinf(h); ci[q] = __cosf(h);
    }
    float cw[NQ], sw[NQ];
#pragma unroll
    for (int q = 0; q < NQ; ++q) {
        const float h = w[q] * 0.5f;
        sw[q] = __sinf(h); cw[q] = __cosf(h);
    }

    // ---- initial product state ----
    const float laneF =
        ((lane & 32) ? si[5]  : ci[5])  *
        ((lane & 16) ? si[6]  : ci[6])  *
        ((lane & 8)  ? si[7]  : ci[7])  *
        ((lane & 4)  ? si[8]  : ci[8])  *
        ((lane & 2)  ? si[9]  : ci[9])  *
        ((lane & 1)  ? si[10] : ci[10]);

    f32x2 v2[16];
#pragma unroll
    for (int k = 0; k < 16; ++k) {
        const float base = laneF * ((k & 8) ? si[0] : ci[0])
                                 * ((k & 4) ? si[1] : ci[1])
                                 * ((k & 2) ? si[2] : ci[2])
                                 * ((k & 1) ? si[3] : ci[3]);
        v2[k].x = base * ci[4];
        v2[k].y = base * si[4];
    }

    // ---- folded per-lane coefficient constants (verified r3/r5/r6) ----
    const float X0m = (lane & 1) ?  sw[0] : -sw[0];
    const float Y0m = (lane & 1) ? -cw[0] :  cw[0];
    const float SS5 = (lane & 32) ?  sw[5] : -sw[5];
    const float C5m = (lane & 32) ? -cw[5] :  cw[5];
    f32x2 Cv5; Cv5.x = cw[5]; Cv5.y = C5m;
    f32x2 Sv5; Sv5.x = SS5;   Sv5.y = sw[5];
    const f32x2 C6v  = b2(((lane & 48) == 48) ? -cw[6]  : cw[6]);
    const f32x2 S6v  = b2((lane & 48) ? sw[6]  : -sw[6]);
    const f32x2 C7v  = b2(((lane & 24) == 24) ? -cw[7]  : cw[7]);
    const f32x2 S7v  = b2((lane & 24) ? sw[7]  : -sw[7]);
    const f32x2 C8v  = b2(((lane & 12) == 12) ? -cw[8]  : cw[8]);
    const f32x2 S8v  = b2((lane & 12) ? sw[8]  : -sw[8]);
    const f32x2 C9v  = b2(((lane & 6)  == 6)  ? -cw[9]  : cw[9]);
    const f32x2 S9v  = b2((lane & 6)  ? sw[9]  : -sw[9]);
    const f32x2 C10v = b2(((lane & 3)  == 3)  ? -cw[10] : cw[10]);
    const f32x2 S10v = b2((lane & 3)  ? sw[10] : -sw[10]);

    // RY4 (comp butterfly), incoming CZ(3,4): sigma1 = -1 iff k odd.
    f32x2 C4p; C4p.x = cw[4];  C4p.y =  cw[4];
    f32x2 S4p; S4p.x = -sw[4]; S4p.y =  sw[4];
    f32x2 C4m; C4m.x = cw[4];  C4m.y = -cw[4];
    f32x2 S4m; S4m.x = sw[4];  S4m.y =  sw[4];

    auto shfl32 = [](float t) { return __shfl_xor(t, 32); };
    auto shfl16 = [](float t) { return __shfl_xor(t, 16); };
    auto dppx8  = [](float t) { return dpp_mov<DPP_XOR8>(t); };
    auto dppx4  = [](float t) { return dpp_mov<DPP_XOR3>(dpp_mov<DPP_XOR7>(t)); };
    auto dppx2  = [](float t) { return dpp_mov<DPP_XOR2>(t); };
    auto dppx1  = [](float t) { return dpp_mov<DPP_XOR1>(t); };

    auto layer = [&](float X0, float Y0) {
        // RY0 on k bit 3 (incoming CZ folded into X0/Y0)
        {
            const f32x2 c0 = b2(cw[0]), s0 = b2(sw[0]);
            const f32x2 x0 = b2(X0),    y0 = b2(Y0);
#pragma unroll
            for (int k = 0; k < 8; ++k) {
                const f32x2 a_ = v2[k], b_ = v2[k | 8];
                v2[k]     = fma2(c0, a_, x0 * b_);
                v2[k | 8] = fma2(s0, a_, y0 * b_);
            }
        }
        RY_K_F(2, 8, cw[1], sw[1])      // RY1, fold CZ(0,1)
        RY_K_F(1, 4, cw[2], sw[2])      // RY2, fold CZ(1,2)
        RY_K_F(0, 2, cw[3], sw[3])      // RY3, fold CZ(2,3)

        // RY4 (component), fold CZ(3,4) (k bit0)
#pragma unroll
        for (int k = 0; k < 16; ++k) {
            const f32x2 s_ = __builtin_shufflevector(v2[k], v2[k], 1, 0);
            v2[k] = (k & 1) ? fma2(C4m, v2[k], S4m * s_)
                            : fma2(C4p, v2[k], S4p * s_);
        }

        RY_DS_B(shfl32, Cv5, Sv5)       // RY5,  fold CZ(4,5)  — DS batched
        RY_DS_B(shfl16, C6v, S6v)       // RY6,  fold CZ(5,6)  — DS batched
        RY_DPP(dppx8,  C7v,  S7v)       // RY7,  fold CZ(6,7)  — DPP
        RY_DPP(dppx4,  C8v,  S8v)       // RY8,  fold CZ(7,8)  — DPP x2
        RY_DPP(dppx2,  C9v,  S9v)       // RY9,  fold CZ(8,9)  — DPP
        RY_DPP(dppx1,  C10v, S10v)      // RY10, fold CZ(9,10) — DPP
        // CZ(10,0) -> folded into next layer's RY0; pure sign after last.
    };

    layer(-sw[0], cw[0]);               // layer 0: RY0 has no incoming CZ
#pragma unroll 1
    for (int l = 1; l < 6; ++l) layer(X0m, Y0m);

    // ---- measurement: out[w] = sum_i amp_i^2 * (1 - 2*bit_w(i)) ----
    f32x2 T = b2(0.f), A3 = b2(0.f), A2 = b2(0.f), A1 = b2(0.f), A0 = b2(0.f);
#pragma unroll
    for (int k = 0; k < 16; ++k) {
        const f32x2 p = v2[k] * v2[k];
        T = T + p;
        if (k & 8) A3 = A3 + p;
        if (k & 4) A2 = A2 + p;
        if (k & 2) A1 = A1 + p;
        if (k & 1) A0 = A0 + p;
    }
    const float tot = T.x + T.y;

    float q[NQ];
    q[0] = tot - 2.f * (A3.x + A3.y);
    q[1] = tot - 2.f * (A2.x + A2.y);
    q[2] = tot - 2.f * (A1.x + A1.y);
    q[3] = tot - 2.f * (A0.x + A0.y);
    q[4] = tot - 2.f * T.y;
    q[5]  = (lane & 32) ? -tot : tot;
    q[6]  = (lane & 16) ? -tot : tot;
    q[7]  = (lane & 8)  ? -tot : tot;
    q[8]  = (lane & 4)  ? -tot : tot;
    q[9]  = (lane & 2)  ? -tot : tot;
    q[10] = (lane & 1)  ? -tot : tot;

    // stage-major wave reduction: 11 independent ops per stage
#pragma unroll
    for (int wq = 0; wq < NQ; ++wq) q[wq] += __shfl_xor(q[wq], 32);
#pragma unroll
    for (int wq = 0; wq < NQ; ++wq) q[wq] += __shfl_xor(q[wq], 16);
#pragma unroll
    for (int wq = 0; wq < NQ; ++wq) q[wq] += dpp_mov<DPP_XOR8>(q[wq]);
#pragma unroll
    for (int wq = 0; wq < NQ; ++wq)
        q[wq] += dpp_mov<DPP_XOR3>(dpp_mov<DPP_XOR7>(q[wq]));
#pragma unroll
    for (int wq = 0; wq < NQ; ++wq) q[wq] += dpp_mov<DPP_XOR2>(q[wq]);
#pragma unroll
    for (int wq = 0; wq < NQ; ++wq) q[wq] += dpp_mov<DPP_XOR1>(q[wq]);

    if (lane == 0) {
#pragma unroll
        for (int wq = 0; wq < NQ; ++wq) out[n * 11 + wq] = q[wq];
    }
}

extern "C" void kernel_launch(void* const* d_in, const int* in_sizes, int n_in,
                              void* d_out, int out_size, void* d_ws, size_t ws_size,
                              hipStream_t stream) {
    const float* x = (const float*)d_in[0];   // [8,256,16] f32
    const float* w = (const float*)d_in[1];   // [11] f32
    float* out = (float*)d_out;               // [8,256,11] f32

    qru_kernel<<<512, 256, 0, stream>>>(x, w, out);
}